// Round 7
// baseline (758.424 us; speedup 1.0000x reference)
//
#include <hip/hip_runtime.h>
#include <hip/hip_bf16.h>

// GNN: 2-layer GraphConv (DGL norm='both'), N=100000, E=1600000.
// Round 7: k_hist rebuilt — one edge/thread, 6250 blocks, direct global
// atomics (r6's 512-block LDS-hist version was latency-starved at 18.8%
// occupancy, 74us). k_place chunk 4096->2048 for 2x blocks. Aggregation
// stays wave-per-node CSR gather (r4/r6 win); CSR build stays bucket-binned.

#define BSH 7                 // 128 nodes per bucket
#define BNODES 128
#define SRCMASK 0x1FFFF       // src < 131072

// ---------------- hist: 1 edge/thread, direct global atomics ----------------
__global__ __launch_bounds__(256) void k_hist(const int* __restrict__ src,
        const int* __restrict__ dst, int* __restrict__ dO,
        int* __restrict__ bcnt, int E) {
    int i = blockIdx.x * 256 + threadIdx.x;
    if (i < E) {
        atomicAdd(&dO[src[i]], 1);
        atomicAdd(&bcnt[dst[i] >> BSH], 1);
    }
}

// ---------------- scan 782 bucket counts in one block ----------------
__global__ void k_bscan(const int* __restrict__ bcnt, int* __restrict__ bstart,
                        int* __restrict__ bcur, int NB, int E) {
    __shared__ int s[1024];
    int t = threadIdx.x;
    int v = (t < NB) ? bcnt[t] : 0;
    s[t] = v;
    __syncthreads();
    for (int o = 1; o < 1024; o <<= 1) {
        int u = (t >= o) ? s[t - o] : 0;
        __syncthreads();
        s[t] += u;
        __syncthreads();
    }
    if (t < NB) { int st = s[t] - v; bstart[t] = st; bcur[t] = st; }
    if (t == 0) bstart[NB] = E;
}

// ---------------- place: bin edges into bucket regions (packed 4B) ----------
// chunk 2048 edges/block; per-(block,bucket) run reservation -> sequential
// appends per bucket stream.
__global__ __launch_bounds__(256) void k_place(const int* __restrict__ src,
        const int* __restrict__ dst, int* __restrict__ bcur,
        int* __restrict__ ebuf, int E, int NB) {
    __shared__ int lh[800], lbase[800];
    int t = threadIdx.x;
    int e0 = blockIdx.x * 2048;
    int e1 = min(e0 + 2048, E);
    for (int i = t; i < NB; i += 256) lh[i] = 0;
    __syncthreads();
    for (int i = e0 + t; i < e1; i += 256) atomicAdd(&lh[dst[i] >> BSH], 1);
    __syncthreads();
    for (int i = t; i < NB; i += 256) {
        int c = lh[i];
        if (c) lbase[i] = atomicAdd(&bcur[i], c);
        lh[i] = 0;
    }
    __syncthreads();
    for (int i = e0 + t; i < e1; i += 256) {
        int d = dst[i], b = d >> BSH;
        int pos = lbase[b] + atomicAdd(&lh[b], 1);
        ebuf[pos] = src[i] | ((d & (BNODES - 1)) << 17);
    }
}

// ---------------- sort2: bucket stream -> per-node CSR + off ends + nI ------
__global__ __launch_bounds__(256) void k_sort2(const int* __restrict__ ebuf,
        const int* __restrict__ bstart, int* __restrict__ csrc,
        int* __restrict__ off, float* __restrict__ nI, int n) {
    __shared__ int cnt[BNODES], cur[BNODES], s[BNODES];
    int t = threadIdx.x, b = blockIdx.x;
    int e0 = bstart[b], e1 = bstart[b + 1];
    if (t < BNODES) cnt[t] = 0;
    __syncthreads();
    for (int i = e0 + t; i < e1; i += 256)
        atomicAdd(&cnt[ebuf[i] >> 17], 1);
    __syncthreads();
    if (t < BNODES) s[t] = cnt[t];
    __syncthreads();
    for (int o = 1; o < BNODES; o <<= 1) {
        int u = (t < BNODES && t >= o) ? s[t - o] : 0;
        __syncthreads();
        if (t < BNODES) s[t] += u;
        __syncthreads();
    }
    if (t < BNODES) {
        cur[t] = e0 + s[t] - cnt[t];          // exclusive start
        int g = b * BNODES + t;
        if (g < n) {
            off[g] = e0 + s[t];               // inclusive end
            nI[g] = rsqrtf(fmaxf((float)cnt[t], 1.0f));
        }
    }
    __syncthreads();
    for (int i = e0 + t; i < e1; i += 256) {
        int p = ebuf[i];
        int pos = atomicAdd(&cur[p >> 17], 1);
        csrc[pos] = p & SRCMASK;
    }
}

__global__ void k_normO(const int* __restrict__ dO, float* __restrict__ nO, int n) {
    int i = blockIdx.x * 256 + threadIdx.x;
    if (i < n) nO[i] = rsqrtf(fmaxf((float)dO[i], 1.0f));
}

// ---------------- GEMM1: h1 = (x*nO) @ W1, 128->64, 4x4 register tile -------
__global__ __launch_bounds__(256) void k_gemm1(const float* __restrict__ x,
                        const float* __restrict__ W1, const float* __restrict__ nO,
                        float* __restrict__ h1, int n) {
    __shared__ float sX[64 * 132];
    __shared__ float sW[128 * 64];
    const int t = threadIdx.x;
    {
        const float4* W4 = (const float4*)W1;
        float4* sW4 = (float4*)sW;
#pragma unroll
        for (int i = 0; i < 8; i++) sW4[t + 256 * i] = W4[t + 256 * i];
    }
    const int rowbase = blockIdx.x * 64;
    {
        const float4* x4 = (const float4*)x;
        float4* sX4 = (float4*)sX;
#pragma unroll
        for (int i = 0; i < 8; i++) {
            int f = t + 256 * i;
            int row = f >> 5, kc = f & 31;
            int grow = rowbase + row;
            float4 v = make_float4(0.f, 0.f, 0.f, 0.f);
            if (grow < n) v = x4[(size_t)grow * 32 + kc];
            sX4[row * 33 + kc] = v;
        }
    }
    __syncthreads();
    const int lane = t & 63, wv = t >> 6;
    const int rg = lane >> 2, cg = lane & 3;
    const int c0 = wv * 16 + cg * 4;
    float acc[4][4] = {};
    for (int kk = 0; kk < 128; kk += 4) {
        float xr[4][4], wr[4][4];
#pragma unroll
        for (int i = 0; i < 4; i++)
            *(float4*)xr[i] = *(const float4*)&sX[(rg + 16 * i) * 132 + kk];
#pragma unroll
        for (int j = 0; j < 4; j++)
            *(float4*)wr[j] = *(const float4*)&sW[(kk + j) * 64 + c0];
#pragma unroll
        for (int j = 0; j < 4; j++)
#pragma unroll
            for (int i = 0; i < 4; i++)
#pragma unroll
                for (int c = 0; c < 4; c++)
                    acc[i][c] = fmaf(xr[i][j], wr[j][c], acc[i][c]);
    }
#pragma unroll
    for (int i = 0; i < 4; i++) {
        int grow = rowbase + rg + 16 * i;
        if (grow < n) {
            float nf = nO[grow];
            float4 o = make_float4(acc[i][0] * nf, acc[i][1] * nf,
                                   acc[i][2] * nf, acc[i][3] * nf);
            *(float4*)&h1[(size_t)grow * 64 + c0] = o;
        }
    }
}

// ---------------- agg1: one wave per node, 64 cols, unroll 8 ----------------
__global__ void k_agg64(const float* __restrict__ h, const int* __restrict__ csrc,
                        const int* __restrict__ off, const float* __restrict__ nI,
                        const float* __restrict__ b1, float* __restrict__ x2, int n) {
    int node = blockIdx.x * 4 + (threadIdx.x >> 6);
    int lane = threadIdx.x & 63;
    if (node >= n) return;
    int s0 = node ? off[node - 1] : 0;
    int s1 = off[node];
    float a0 = 0.f, a1 = 0.f, a2 = 0.f, a3 = 0.f;
    float a4 = 0.f, a5 = 0.f, a6 = 0.f, a7 = 0.f;
    int e = s0;
    for (; e + 7 < s1; e += 8) {
        int i0 = csrc[e], i1 = csrc[e + 1], i2 = csrc[e + 2], i3 = csrc[e + 3];
        int i4 = csrc[e + 4], i5 = csrc[e + 5], i6 = csrc[e + 6], i7 = csrc[e + 7];
        a0 += h[(size_t)i0 * 64 + lane];
        a1 += h[(size_t)i1 * 64 + lane];
        a2 += h[(size_t)i2 * 64 + lane];
        a3 += h[(size_t)i3 * 64 + lane];
        a4 += h[(size_t)i4 * 64 + lane];
        a5 += h[(size_t)i5 * 64 + lane];
        a6 += h[(size_t)i6 * 64 + lane];
        a7 += h[(size_t)i7 * 64 + lane];
    }
    for (; e < s1; e++) a0 += h[(size_t)csrc[e] * 64 + lane];
    float acc = ((a0 + a1) + (a2 + a3)) + ((a4 + a5) + (a6 + a7));
    x2[(size_t)node * 64 + lane] = fmaxf(fmaf(acc, nI[node], b1[lane]), 0.f);
}

// ---------------- GEMM2: h2 = (x2*nO) @ W2, 64->32, 4x4 register tile -------
__global__ __launch_bounds__(256) void k_gemm2(const float* __restrict__ x2,
                        const float* __restrict__ W2, const float* __restrict__ nO,
                        float* __restrict__ h2, int n) {
    __shared__ float sX[128 * 68];
    __shared__ float sW[64 * 32];
    const int t = threadIdx.x;
    {
        const float4* W4 = (const float4*)W2;
        float4* sW4 = (float4*)sW;
#pragma unroll
        for (int i = 0; i < 2; i++) sW4[t + 256 * i] = W4[t + 256 * i];
    }
    const int rowbase = blockIdx.x * 128;
    {
        const float4* x4 = (const float4*)x2;
        float4* sX4 = (float4*)sX;
#pragma unroll
        for (int i = 0; i < 8; i++) {
            int f = t + 256 * i;
            int row = f >> 4, kc = f & 15;
            int grow = rowbase + row;
            float4 v = make_float4(0.f, 0.f, 0.f, 0.f);
            if (grow < n) v = x4[(size_t)grow * 16 + kc];
            sX4[row * 17 + kc] = v;
        }
    }
    __syncthreads();
    const int lane = t & 63, wv = t >> 6;
    const int whalf = wv >> 1, chalf = wv & 1;
    const int rg = lane >> 2, cg = lane & 3;
    const int c0 = chalf * 16 + cg * 4;
    const int rloc = whalf * 64 + rg;
    float acc[4][4] = {};
    for (int kk = 0; kk < 64; kk += 4) {
        float xr[4][4], wr[4][4];
#pragma unroll
        for (int i = 0; i < 4; i++)
            *(float4*)xr[i] = *(const float4*)&sX[(rloc + 16 * i) * 68 + kk];
#pragma unroll
        for (int j = 0; j < 4; j++)
            *(float4*)wr[j] = *(const float4*)&sW[(kk + j) * 32 + c0];
#pragma unroll
        for (int j = 0; j < 4; j++)
#pragma unroll
            for (int i = 0; i < 4; i++)
#pragma unroll
                for (int c = 0; c < 4; c++)
                    acc[i][c] = fmaf(xr[i][j], wr[j][c], acc[i][c]);
    }
#pragma unroll
    for (int i = 0; i < 4; i++) {
        int grow = rowbase + rloc + 16 * i;
        if (grow < n) {
            float nf = nO[grow];
            float4 o = make_float4(acc[i][0] * nf, acc[i][1] * nf,
                                   acc[i][2] * nf, acc[i][3] * nf);
            *(float4*)&h2[(size_t)grow * 32 + c0] = o;
        }
    }
}

// ---------------- agg2: one wave per node, 32 cols ----------------
__global__ void k_agg32(const float* __restrict__ h, const int* __restrict__ csrc,
                        const int* __restrict__ off, const float* __restrict__ nI,
                        const float* __restrict__ b2, float* __restrict__ out, int n) {
    int node = blockIdx.x * 4 + (threadIdx.x >> 6);
    int lane = threadIdx.x & 63;
    int half = lane >> 5, col = lane & 31;
    if (node >= n) return;
    int s0 = node ? off[node - 1] : 0;
    int s1 = off[node];
    float a0 = 0.f, a1 = 0.f, a2 = 0.f, a3 = 0.f;
    int e = s0 + half;
    for (; e + 6 < s1; e += 8) {
        a0 += h[(size_t)csrc[e] * 32 + col];
        a1 += h[(size_t)csrc[e + 2] * 32 + col];
        a2 += h[(size_t)csrc[e + 4] * 32 + col];
        a3 += h[(size_t)csrc[e + 6] * 32 + col];
    }
    for (; e < s1; e += 2) a0 += h[(size_t)csrc[e] * 32 + col];
    float acc = (a0 + a1) + (a2 + a3);
    acc += __shfl(acc, lane ^ 32, 64);
    if (half == 0) out[(size_t)node * 32 + col] = fmaf(acc, nI[node], b2[col]);
}

extern "C" void kernel_launch(void* const* d_in, const int* in_sizes, int n_in,
                              void* d_out, int out_size, void* d_ws, size_t ws_size,
                              hipStream_t stream) {
    const float* x   = (const float*)d_in[0];  // [N,128]
    const int*   src = (const int*)d_in[1];    // [E]
    const int*   dst = (const int*)d_in[2];    // [E]
    const float* W1  = (const float*)d_in[3];  // [128,64]
    const float* b1  = (const float*)d_in[4];  // [64]
    const float* W2  = (const float*)d_in[5];  // [64,32]
    const float* b2  = (const float*)d_in[6];  // [32]
    float* out = (float*)d_out;                // [N,32]

    const int N = in_sizes[0] / 128;           // 100000
    const int E = in_sizes[1];                 // 1600000
    const int NB = (N + BNODES - 1) / BNODES;  // 782 buckets

    char* wsb = (char*)d_ws;
    int*   dO     = (int*)wsb;    wsb += (size_t)N * 4;
    float* nO     = (float*)wsb;  wsb += (size_t)N * 4;
    float* nI     = (float*)wsb;  wsb += (size_t)N * 4;
    int*   off    = (int*)wsb;    wsb += (size_t)N * 4;
    int*   bcnt   = (int*)wsb;    wsb += 800 * 4;
    int*   bstart = (int*)wsb;    wsb += 800 * 4;
    int*   bcur   = (int*)wsb;    wsb += 800 * 4;
    int*   csrc   = (int*)wsb;    wsb += (size_t)E * 4;
    float* h1     = (float*)wsb;  wsb += (size_t)N * 64 * 4;
    float* x2     = (float*)wsb;  wsb += (size_t)N * 64 * 4;
    float* h2     = h1;           // h1 dead after k_agg64
    int*   ebuf   = (int*)x2;     // ebuf dead before k_agg64 writes x2

    hipMemsetAsync(dO,   0, (size_t)N * sizeof(int), stream);
    hipMemsetAsync(bcnt, 0, (size_t)NB * sizeof(int), stream);

    // CSR build via coarse bucket binning (no per-node random scatter)
    k_hist<<<(E + 255) / 256, 256, 0, stream>>>(src, dst, dO, bcnt, E);
    k_bscan<<<1, 1024, 0, stream>>>(bcnt, bstart, bcur, NB, E);
    k_place<<<(E + 2047) / 2048, 256, 0, stream>>>(src, dst, bcur, ebuf, E, NB);
    k_sort2<<<NB, 256, 0, stream>>>(ebuf, bstart, csrc, off, nI, N);
    k_normO<<<(N + 255) / 256, 256, 0, stream>>>(dO, nO, N);

    // layer 1
    k_gemm1<<<(N + 63) / 64, 256, 0, stream>>>(x, W1, nO, h1, N);
    k_agg64<<<(N + 3) / 4, 256, 0, stream>>>(h1, csrc, off, nI, b1, x2, N);

    // layer 2
    k_gemm2<<<(N + 127) / 128, 256, 0, stream>>>(x2, W2, nO, h2, N);
    k_agg32<<<(N + 3) / 4, 256, 0, stream>>>(h2, csrc, off, nI, b2, out, N);
}

// Round 8
// 383.875 us; speedup vs baseline: 1.9757x; 1.9757x over previous
//
#include <hip/hip_runtime.h>
#include <hip/hip_bf16.h>

// GNN: 2-layer GraphConv (DGL norm='both'), N=100000, E=1600000.
// Round 8: fixed-capacity buckets (CAP=2560/bucket) eliminate the global
// bucket histogram entirely — r7's 1.6M atomics onto 782 counters serialized
// at ~200cyc/op (431us). Remaining atomics: dO (100k targets, low contention,
// own max-occupancy kernel) and place's run reservation (306k over 782
// line-padded counters). nO folded into GEMMs. Aggregation stays
// wave-per-node CSR gather.

#define BSH 7                 // 128 nodes per bucket
#define BNODES 128
#define SRCMASK 0x1FFFF       // src < 131072
#define CAP 2560              // bucket capacity (mean 2048, sigma~45: 11 sd)

// ---------------- out-degree: 1 edge/thread, 100k-target atomics ------------
__global__ __launch_bounds__(256) void k_degO(const int* __restrict__ src,
        int* __restrict__ dO, int E) {
    int i = blockIdx.x * 256 + threadIdx.x;
    if (i < E) atomicAdd(&dO[src[i]], 1);
}

// ---------------- init line-padded bucket cursors ----------------
__global__ void k_initcur(int* __restrict__ bcur, int NB) {
    int t = blockIdx.x * 256 + threadIdx.x;
    if (t < NB) bcur[t * 16] = t * CAP;
}

// ---------------- place: bin edges into fixed-cap bucket regions ------------
// chunk 4096 edges/block (391 blocks, r6-proven); per-(block,bucket) run
// reservation on line-padded bcur -> sequential packed appends.
__global__ __launch_bounds__(256) void k_place(const int* __restrict__ src,
        const int* __restrict__ dst, int* __restrict__ bcur,
        int* __restrict__ ebuf, int E, int NB) {
    __shared__ int lh[800], lbase[800];
    int t = threadIdx.x;
    int e0 = blockIdx.x * 4096;
    int e1 = min(e0 + 4096, E);
    for (int i = t; i < NB; i += 256) lh[i] = 0;
    __syncthreads();
    for (int i = e0 + t; i < e1; i += 256) atomicAdd(&lh[dst[i] >> BSH], 1);
    __syncthreads();
    for (int i = t; i < NB; i += 256) {
        int c = lh[i];
        if (c) lbase[i] = atomicAdd(&bcur[i * 16], c);
        lh[i] = 0;
    }
    __syncthreads();
    for (int i = e0 + t; i < e1; i += 256) {
        int d = dst[i], b = d >> BSH;
        int pos = lbase[b] + atomicAdd(&lh[b], 1);
        ebuf[pos] = src[i] | ((d & (BNODES - 1)) << 17);
    }
}

// ---------------- sort2: bucket stream -> per-node CSR + ostart/oend + nI ---
__global__ __launch_bounds__(256) void k_sort2(const int* __restrict__ ebuf,
        const int* __restrict__ bcur, int* __restrict__ csrc,
        int* __restrict__ ostart, int* __restrict__ oend,
        float* __restrict__ nI, int n) {
    __shared__ int cnt[BNODES], cur[BNODES], s[BNODES];
    int t = threadIdx.x, b = blockIdx.x;
    int e0 = b * CAP, e1 = bcur[b * 16];
    if (t < BNODES) cnt[t] = 0;
    __syncthreads();
    for (int i = e0 + t; i < e1; i += 256)
        atomicAdd(&cnt[ebuf[i] >> 17], 1);
    __syncthreads();
    if (t < BNODES) s[t] = cnt[t];
    __syncthreads();
    for (int o = 1; o < BNODES; o <<= 1) {
        int u = (t < BNODES && t >= o) ? s[t - o] : 0;
        __syncthreads();
        if (t < BNODES) s[t] += u;
        __syncthreads();
    }
    if (t < BNODES) {
        int st = e0 + s[t] - cnt[t];
        cur[t] = st;
        int g = b * BNODES + t;
        if (g < n) {
            ostart[g] = st;
            oend[g] = e0 + s[t];
            nI[g] = rsqrtf(fmaxf((float)cnt[t], 1.0f));
        }
    }
    __syncthreads();
    for (int i = e0 + t; i < e1; i += 256) {
        int p = ebuf[i];
        int pos = atomicAdd(&cur[p >> 17], 1);
        csrc[pos] = p & SRCMASK;
    }
}

// ---------------- GEMM1: h1 = (x*rsqrt(dO)) @ W1, 128->64, 4x4 tile ---------
__global__ __launch_bounds__(256) void k_gemm1(const float* __restrict__ x,
                        const float* __restrict__ W1, const int* __restrict__ dO,
                        float* __restrict__ h1, int n) {
    __shared__ float sX[64 * 132];
    __shared__ float sW[128 * 64];
    const int t = threadIdx.x;
    {
        const float4* W4 = (const float4*)W1;
        float4* sW4 = (float4*)sW;
#pragma unroll
        for (int i = 0; i < 8; i++) sW4[t + 256 * i] = W4[t + 256 * i];
    }
    const int rowbase = blockIdx.x * 64;
    {
        const float4* x4 = (const float4*)x;
        float4* sX4 = (float4*)sX;
#pragma unroll
        for (int i = 0; i < 8; i++) {
            int f = t + 256 * i;
            int row = f >> 5, kc = f & 31;
            int grow = rowbase + row;
            float4 v = make_float4(0.f, 0.f, 0.f, 0.f);
            if (grow < n) v = x4[(size_t)grow * 32 + kc];
            sX4[row * 33 + kc] = v;
        }
    }
    __syncthreads();
    const int lane = t & 63, wv = t >> 6;
    const int rg = lane >> 2, cg = lane & 3;
    const int c0 = wv * 16 + cg * 4;
    float acc[4][4] = {};
    for (int kk = 0; kk < 128; kk += 4) {
        float xr[4][4], wr[4][4];
#pragma unroll
        for (int i = 0; i < 4; i++)
            *(float4*)xr[i] = *(const float4*)&sX[(rg + 16 * i) * 132 + kk];
#pragma unroll
        for (int j = 0; j < 4; j++)
            *(float4*)wr[j] = *(const float4*)&sW[(kk + j) * 64 + c0];
#pragma unroll
        for (int j = 0; j < 4; j++)
#pragma unroll
            for (int i = 0; i < 4; i++)
#pragma unroll
                for (int c = 0; c < 4; c++)
                    acc[i][c] = fmaf(xr[i][j], wr[j][c], acc[i][c]);
    }
#pragma unroll
    for (int i = 0; i < 4; i++) {
        int grow = rowbase + rg + 16 * i;
        if (grow < n) {
            float nf = rsqrtf(fmaxf((float)dO[grow], 1.0f));
            float4 o = make_float4(acc[i][0] * nf, acc[i][1] * nf,
                                   acc[i][2] * nf, acc[i][3] * nf);
            *(float4*)&h1[(size_t)grow * 64 + c0] = o;
        }
    }
}

// ---------------- agg1: one wave per node, 64 cols, unroll 8 ----------------
__global__ void k_agg64(const float* __restrict__ h, const int* __restrict__ csrc,
                        const int* __restrict__ ostart, const int* __restrict__ oend,
                        const float* __restrict__ nI, const float* __restrict__ b1,
                        float* __restrict__ x2, int n) {
    int node = blockIdx.x * 4 + (threadIdx.x >> 6);
    int lane = threadIdx.x & 63;
    if (node >= n) return;
    int s0 = ostart[node];
    int s1 = oend[node];
    float a0 = 0.f, a1 = 0.f, a2 = 0.f, a3 = 0.f;
    float a4 = 0.f, a5 = 0.f, a6 = 0.f, a7 = 0.f;
    int e = s0;
    for (; e + 7 < s1; e += 8) {
        int i0 = csrc[e], i1 = csrc[e + 1], i2 = csrc[e + 2], i3 = csrc[e + 3];
        int i4 = csrc[e + 4], i5 = csrc[e + 5], i6 = csrc[e + 6], i7 = csrc[e + 7];
        a0 += h[(size_t)i0 * 64 + lane];
        a1 += h[(size_t)i1 * 64 + lane];
        a2 += h[(size_t)i2 * 64 + lane];
        a3 += h[(size_t)i3 * 64 + lane];
        a4 += h[(size_t)i4 * 64 + lane];
        a5 += h[(size_t)i5 * 64 + lane];
        a6 += h[(size_t)i6 * 64 + lane];
        a7 += h[(size_t)i7 * 64 + lane];
    }
    for (; e < s1; e++) a0 += h[(size_t)csrc[e] * 64 + lane];
    float acc = ((a0 + a1) + (a2 + a3)) + ((a4 + a5) + (a6 + a7));
    x2[(size_t)node * 64 + lane] = fmaxf(fmaf(acc, nI[node], b1[lane]), 0.f);
}

// ---------------- GEMM2: h2 = (x2*rsqrt(dO)) @ W2, 64->32, 4x4 tile ---------
__global__ __launch_bounds__(256) void k_gemm2(const float* __restrict__ x2,
                        const float* __restrict__ W2, const int* __restrict__ dO,
                        float* __restrict__ h2, int n) {
    __shared__ float sX[128 * 68];
    __shared__ float sW[64 * 32];
    const int t = threadIdx.x;
    {
        const float4* W4 = (const float4*)W2;
        float4* sW4 = (float4*)sW;
#pragma unroll
        for (int i = 0; i < 2; i++) sW4[t + 256 * i] = W4[t + 256 * i];
    }
    const int rowbase = blockIdx.x * 128;
    {
        const float4* x4 = (const float4*)x2;
        float4* sX4 = (float4*)sX;
#pragma unroll
        for (int i = 0; i < 8; i++) {
            int f = t + 256 * i;
            int row = f >> 4, kc = f & 15;
            int grow = rowbase + row;
            float4 v = make_float4(0.f, 0.f, 0.f, 0.f);
            if (grow < n) v = x4[(size_t)grow * 16 + kc];
            sX4[row * 17 + kc] = v;
        }
    }
    __syncthreads();
    const int lane = t & 63, wv = t >> 6;
    const int whalf = wv >> 1, chalf = wv & 1;
    const int rg = lane >> 2, cg = lane & 3;
    const int c0 = chalf * 16 + cg * 4;
    const int rloc = whalf * 64 + rg;
    float acc[4][4] = {};
    for (int kk = 0; kk < 64; kk += 4) {
        float xr[4][4], wr[4][4];
#pragma unroll
        for (int i = 0; i < 4; i++)
            *(float4*)xr[i] = *(const float4*)&sX[(rloc + 16 * i) * 68 + kk];
#pragma unroll
        for (int j = 0; j < 4; j++)
            *(float4*)wr[j] = *(const float4*)&sW[(kk + j) * 32 + c0];
#pragma unroll
        for (int j = 0; j < 4; j++)
#pragma unroll
            for (int i = 0; i < 4; i++)
#pragma unroll
                for (int c = 0; c < 4; c++)
                    acc[i][c] = fmaf(xr[i][j], wr[j][c], acc[i][c]);
    }
#pragma unroll
    for (int i = 0; i < 4; i++) {
        int grow = rowbase + rloc + 16 * i;
        if (grow < n) {
            float nf = rsqrtf(fmaxf((float)dO[grow], 1.0f));
            float4 o = make_float4(acc[i][0] * nf, acc[i][1] * nf,
                                   acc[i][2] * nf, acc[i][3] * nf);
            *(float4*)&h2[(size_t)grow * 32 + c0] = o;
        }
    }
}

// ---------------- agg2: one wave per node, 32 cols ----------------
__global__ void k_agg32(const float* __restrict__ h, const int* __restrict__ csrc,
                        const int* __restrict__ ostart, const int* __restrict__ oend,
                        const float* __restrict__ nI, const float* __restrict__ b2,
                        float* __restrict__ out, int n) {
    int node = blockIdx.x * 4 + (threadIdx.x >> 6);
    int lane = threadIdx.x & 63;
    int half = lane >> 5, col = lane & 31;
    if (node >= n) return;
    int s0 = ostart[node];
    int s1 = oend[node];
    float a0 = 0.f, a1 = 0.f, a2 = 0.f, a3 = 0.f;
    int e = s0 + half;
    for (; e + 6 < s1; e += 8) {
        a0 += h[(size_t)csrc[e] * 32 + col];
        a1 += h[(size_t)csrc[e + 2] * 32 + col];
        a2 += h[(size_t)csrc[e + 4] * 32 + col];
        a3 += h[(size_t)csrc[e + 6] * 32 + col];
    }
    for (; e < s1; e += 2) a0 += h[(size_t)csrc[e] * 32 + col];
    float acc = (a0 + a1) + (a2 + a3);
    acc += __shfl(acc, lane ^ 32, 64);
    if (half == 0) out[(size_t)node * 32 + col] = fmaf(acc, nI[node], b2[col]);
}

extern "C" void kernel_launch(void* const* d_in, const int* in_sizes, int n_in,
                              void* d_out, int out_size, void* d_ws, size_t ws_size,
                              hipStream_t stream) {
    const float* x   = (const float*)d_in[0];  // [N,128]
    const int*   src = (const int*)d_in[1];    // [E]
    const int*   dst = (const int*)d_in[2];    // [E]
    const float* W1  = (const float*)d_in[3];  // [128,64]
    const float* b1  = (const float*)d_in[4];  // [64]
    const float* W2  = (const float*)d_in[5];  // [64,32]
    const float* b2  = (const float*)d_in[6];  // [32]
    float* out = (float*)d_out;                // [N,32]

    const int N = in_sizes[0] / 128;           // 100000
    const int E = in_sizes[1];                 // 1600000
    const int NB = (N + BNODES - 1) / BNODES;  // 782 buckets

    char* wsb = (char*)d_ws;
    int*   dO     = (int*)wsb;    wsb += (size_t)N * 4;
    float* nI     = (float*)wsb;  wsb += (size_t)N * 4;
    int*   ostart = (int*)wsb;    wsb += (size_t)N * 4;
    int*   oend   = (int*)wsb;    wsb += (size_t)N * 4;
    int*   bcur   = (int*)wsb;    wsb += (size_t)800 * 16 * 4;   // line-padded
    int*   csrc   = (int*)wsb;    wsb += (size_t)NB * CAP * 4;   // 8.0 MB
    float* h1     = (float*)wsb;  wsb += (size_t)N * 64 * 4;     // 25.6 MB
    float* x2     = (float*)wsb;  wsb += (size_t)N * 64 * 4;     // 25.6 MB
    float* h2     = h1;           // h1 dead after k_agg64
    int*   ebuf   = (int*)x2;     // 8.0 MB region; dead before agg64 writes x2

    hipMemsetAsync(dO, 0, (size_t)N * sizeof(int), stream);

    // CSR build: fixed-cap bucket binning (no global histogram, no scan)
    k_degO<<<(E + 255) / 256, 256, 0, stream>>>(src, dO, E);
    k_initcur<<<(NB + 255) / 256, 256, 0, stream>>>(bcur, NB);
    k_place<<<(E + 4095) / 4096, 256, 0, stream>>>(src, dst, bcur, ebuf, E, NB);
    k_sort2<<<NB, 256, 0, stream>>>(ebuf, bcur, csrc, ostart, oend, nI, N);

    // layer 1
    k_gemm1<<<(N + 63) / 64, 256, 0, stream>>>(x, W1, dO, h1, N);
    k_agg64<<<(N + 3) / 4, 256, 0, stream>>>(h1, csrc, ostart, oend, nI, b1, x2, N);

    // layer 2
    k_gemm2<<<(N + 127) / 128, 256, 0, stream>>>(x2, W2, dO, h2, N);
    k_agg32<<<(N + 3) / 4, 256, 0, stream>>>(h2, csrc, ostart, oend, nI, b2, out, N);
}